// Round 2
// baseline (1554.269 us; speedup 1.0000x reference)
//
#include <hip/hip_runtime.h>

// ============================================================================
// KnowledgeGraphEncoder: 2-layer dense GAT, N=4096, H=4.
// bf16 MFMA GEMMs, fp32 softmax logits, per-head P materialization (ws ~146MB).
// ============================================================================

typedef unsigned short u16;
using short8  = __attribute__((ext_vector_type(8))) short;
using float4v = __attribute__((ext_vector_type(4))) float;

#define NN 4096
#define NHEADS 4

__device__ __forceinline__ u16 f2bf(float f) {
  union { float f; unsigned u; } v; v.f = f;
  unsigned u = v.u;
  return (u16)((u + 0x7FFFu + ((u >> 16) & 1u)) >> 16);   // RNE
}
__device__ __forceinline__ float bf2f(u16 x) {
  union { unsigned u; float f; } v; v.u = ((unsigned)x) << 16; return v.f;
}

// ---------------------------------------------------------------- cast fp32->bf16
__global__ __launch_bounds__(256) void cast_f32_bf16(const float* __restrict__ in,
                                                     u16* __restrict__ out, int n) {
  int i = blockIdx.x * 256 + threadIdx.x;
  if (i < n) out[i] = f2bf(in[i]);
}

// ------------------------------------------------- transpose+cast fp32 -> bf16
// in [z][R][C] -> out [z][C][R]
__global__ __launch_bounds__(256) void transcast_f32(const float* __restrict__ in,
                                                     u16* __restrict__ out, int R, int C) {
  __shared__ float t[32][33];
  size_t zoff = (size_t)blockIdx.z * R * C;
  in += zoff; out += zoff;
  int c0 = blockIdx.x * 32, r0 = blockIdx.y * 32;
  int tx = threadIdx.x & 31, ty = threadIdx.x >> 5;
#pragma unroll
  for (int i = 0; i < 32; i += 8)
    t[ty + i][tx] = in[(size_t)(r0 + ty + i) * C + (c0 + tx)];
  __syncthreads();
#pragma unroll
  for (int i = 0; i < 32; i += 8)
    out[(size_t)(c0 + ty + i) * R + (r0 + tx)] = f2bf(t[tx][ty + i]);
}

// ------------------------------------------------- transpose bf16 -> bf16
__global__ __launch_bounds__(256) void trans_u16(const u16* __restrict__ in,
                                                 u16* __restrict__ out, int R, int C) {
  __shared__ u16 t[32][33];
  size_t zoff = (size_t)blockIdx.z * R * C;
  in += zoff; out += zoff;
  int c0 = blockIdx.x * 32, r0 = blockIdx.y * 32;
  int tx = threadIdx.x & 31, ty = threadIdx.x >> 5;
#pragma unroll
  for (int i = 0; i < 32; i += 8)
    t[ty + i][tx] = in[(size_t)(r0 + ty + i) * C + (c0 + tx)];
  __syncthreads();
#pragma unroll
  for (int i = 0; i < 32; i += 8)
    out[(size_t)(c0 + ty + i) * R + (r0 + tx)] = t[tx][ty + i];
}

// ------------------------------------------------- wa[side][h][f] = sum_o W[h][f][o]*a[h][side*O+o]
__global__ __launch_bounds__(256) void wa_kernel(const float* __restrict__ W,
                                                 const float* __restrict__ a,
                                                 float* __restrict__ wa, int F, int O) {
  int gw = blockIdx.x * 4 + (threadIdx.x >> 6);
  int lane = threadIdx.x & 63;
  int total = 2 * NHEADS * F;
  if (gw >= total) return;
  int side = gw / (NHEADS * F);
  int rem = gw - side * NHEADS * F;
  int h = rem / F, f = rem - h * F;
  const float* wrow = W + ((size_t)h * F + f) * O;
  const float* av = a + (size_t)h * 2 * O + (size_t)side * O;
  float s = 0.f;
  for (int o = lane; o < O; o += 64) s += wrow[o] * av[o];
#pragma unroll
  for (int off = 32; off > 0; off >>= 1) s += __shfl_down(s, off);
  if (lane == 0) wa[gw] = s;
}

// ------------------------------------------------- s[side][h][n] from fp32 X
__global__ __launch_bounds__(256) void s_kernel_f32(const float* __restrict__ X,
                                                    const float* __restrict__ wa,
                                                    float* __restrict__ sout, int F) {
  int gw = blockIdx.x * 4 + (threadIdx.x >> 6);
  int lane = threadIdx.x & 63;
  if (gw >= 2 * NHEADS * NN) return;
  int n = gw & (NN - 1);
  int sh = gw >> 12;
  const float* x = X + (size_t)n * F;
  const float* w = wa + (size_t)sh * F;
  float s = 0.f;
  for (int f = lane; f < F; f += 64) s += x[f] * w[f];
#pragma unroll
  for (int off = 32; off > 0; off >>= 1) s += __shfl_down(s, off);
  if (lane == 0) sout[gw] = s;
}

// ------------------------------------------------- s[side][h][n] from bf16 X
__global__ __launch_bounds__(256) void s_kernel_bf16(const u16* __restrict__ X,
                                                     const float* __restrict__ wa,
                                                     float* __restrict__ sout, int F) {
  int gw = blockIdx.x * 4 + (threadIdx.x >> 6);
  int lane = threadIdx.x & 63;
  if (gw >= 2 * NHEADS * NN) return;
  int n = gw & (NN - 1);
  int sh = gw >> 12;
  const u16* x = X + (size_t)n * F;
  const float* w = wa + (size_t)sh * F;
  float s = 0.f;
  for (int f = lane; f < F; f += 64) s += bf2f(x[f]) * w[f];
#pragma unroll
  for (int off = 32; off > 0; off >>= 1) s += __shfl_down(s, off);
  if (lane == 0) sout[gw] = s;
}

// ------------------------------------------------- C[h] = max(0, max_i ssrc + max_j sdst)
__global__ __launch_bounds__(256) void cmax_kernel(const float* __restrict__ s,
                                                   float* __restrict__ Cout) {
  int h = blockIdx.x, tid = threadIdx.x;
  const float* ss = s + (size_t)h * NN;
  const float* sd = s + (size_t)(NHEADS + h) * NN;
  float ms = -1e30f, md = -1e30f;
  for (int i = tid; i < NN; i += 256) { ms = fmaxf(ms, ss[i]); md = fmaxf(md, sd[i]); }
  __shared__ float r1[4], r2[4];
#pragma unroll
  for (int off = 32; off > 0; off >>= 1) {
    ms = fmaxf(ms, __shfl_down(ms, off));
    md = fmaxf(md, __shfl_down(md, off));
  }
  if ((tid & 63) == 0) { r1[tid >> 6] = ms; r2[tid >> 6] = md; }
  __syncthreads();
  if (tid == 0) {
    ms = fmaxf(fmaxf(r1[0], r1[1]), fmaxf(r1[2], r1[3]));
    md = fmaxf(fmaxf(r2[0], r2[1]), fmaxf(r2[2], r2[3]));
    Cout[h] = fmaxf(ms + md, 0.0f);
  }
}

// ------------------------------------------------- per-head P' = exp(att - C[h]) bf16, l = rowsum
__global__ __launch_bounds__(256) void pexp_h_kernel(const int* __restrict__ adj,
                                                     const float* __restrict__ ew,
                                                     const float* __restrict__ s,
                                                     const float* __restrict__ Cmax,
                                                     u16* __restrict__ P,
                                                     float* __restrict__ L, int h) {
  int i = blockIdx.x, tid = threadIdx.x;
  float sr = s[(size_t)h * NN + i];
  float C = Cmax[h];
  const float* sd = s + (size_t)(NHEADS + h) * NN;
  const int* arow = adj + (size_t)i * NN;
  const float* wrow = ew + (size_t)i * NN;
  float lacc = 0.f;
  for (int j = tid; j < NN; j += 256) {
    bool m = (arow[j] != 0) || (j == i);
    float x = sr + sd[j];
    float e = x > 0.f ? x : 0.2f * x;
    float v = (m ? e : -9e15f) * wrow[j];
    float p = __expf(v - C);
    P[(size_t)i * NN + j] = f2bf(p);
    lacc += p;
  }
  __shared__ float red[4];
#pragma unroll
  for (int off = 32; off > 0; off >>= 1) lacc += __shfl_down(lacc, off);
  if ((tid & 63) == 0) red[tid >> 6] = lacc;
  __syncthreads();
  if (tid == 0) L[(size_t)h * NN + i] = red[0] + red[1] + red[2] + red[3];
}

// ------------------------------------------------- 128x128 bf16 MFMA GEMM, B^T input
// MODE 0: bf16 store (per-z strides)
// MODE 1: fp32 store of v + bias[col]
// MODE 2: C[idx] += elu(v / l[row])          (layer-0 attn, per-head launch)
// MODE 3: C[idx] += 0.25f * v / l[row]       (layer-1 attn, per-head launch)
template <int MODE>
__global__ __launch_bounds__(256, 2) void gemm_bt(const u16* __restrict__ A,
                                                  const u16* __restrict__ Bt,
                                                  void* __restrict__ Cout,
                                                  const float* __restrict__ rowscale,
                                                  const float* __restrict__ bias,
                                                  int K, int ldc, int coloff,
                                                  size_t aStride, size_t bStride,
                                                  size_t cStride) {
  int h = blockIdx.z;
  const u16* Ab = A + (size_t)h * aStride;
  const u16* Bb = Bt + (size_t)h * bStride;
  int row0 = blockIdx.y * 128;
  int col0 = blockIdx.x * 128;

  __shared__ u16 ldsA[128 * 32];
  __shared__ u16 ldsB[128 * 32];

  int tid = threadIdx.x;
  int wave = tid >> 6, lane = tid & 63;
  int wm = wave >> 1, wn = wave & 1;
  int lm = lane & 15, kq = (lane >> 4) * 8;

  float4v acc[4][4] = {};

  for (int k0 = 0; k0 < K; k0 += 32) {
    __syncthreads();
#pragma unroll
    for (int p = 0; p < 2; p++) {
      int e = (p * 256 + tid) * 8;
      int r = e >> 5, c = e & 31;
      *(short8*)(&ldsA[e]) = *(const short8*)(Ab + (size_t)(row0 + r) * K + (k0 + c));
      *(short8*)(&ldsB[e]) = *(const short8*)(Bb + (size_t)(col0 + r) * K + (k0 + c));
    }
    __syncthreads();
    short8 af[4], bf[4];
#pragma unroll
    for (int s = 0; s < 4; s++) {
      af[s] = *(const short8*)(&ldsA[(wm * 64 + s * 16 + lm) * 32 + kq]);
      bf[s] = *(const short8*)(&ldsB[(wn * 64 + s * 16 + lm) * 32 + kq]);
    }
#pragma unroll
    for (int i = 0; i < 4; i++)
#pragma unroll
      for (int j = 0; j < 4; j++)
        acc[i][j] = __builtin_amdgcn_mfma_f32_16x16x32_bf16(af[i], bf[j], acc[i][j], 0, 0, 0);
  }

#pragma unroll
  for (int i = 0; i < 4; i++) {
#pragma unroll
    for (int j = 0; j < 4; j++) {
#pragma unroll
      for (int r = 0; r < 4; r++) {
        int grow = row0 + wm * 64 + i * 16 + (lane >> 4) * 4 + r;
        int gcol = col0 + wn * 64 + j * 16 + lm;
        float v = acc[i][j][r];
        size_t idx = (size_t)grow * ldc + coloff + gcol;
        if constexpr (MODE == 0) {
          ((u16*)Cout)[(size_t)h * cStride + idx] = f2bf(v);
        } else if constexpr (MODE == 1) {
          ((float*)Cout)[idx] = v + bias[coloff + gcol];
        } else if constexpr (MODE == 2) {
          v *= (1.0f / rowscale[grow]);
          v = v > 0.f ? v : (__expf(v) - 1.f);
          ((float*)Cout)[idx] += v;
        } else {
          v *= (1.0f / rowscale[grow]);
          ((float*)Cout)[idx] += 0.25f * v;
        }
      }
    }
  }
}

// ------------------------------------------------- LN layer 0: LN(x) -> elu -> bf16
__global__ __launch_bounds__(256) void ln0_kernel(const float* __restrict__ xin,
                                                  const float* __restrict__ g,
                                                  const float* __restrict__ b,
                                                  u16* __restrict__ h1b) {
  const int C = 2048;
  int n = blockIdx.x, tid = threadIdx.x;
  __shared__ float red[2][4];
  __shared__ float mrs[2];
  float sum = 0.f, sq = 0.f;
  const float* xr = xin + (size_t)n * C;
  for (int c = tid; c < C; c += 256) {
    float x = xr[c];
    sum += x; sq += x * x;
  }
#pragma unroll
  for (int off = 32; off > 0; off >>= 1) { sum += __shfl_down(sum, off); sq += __shfl_down(sq, off); }
  if ((tid & 63) == 0) { red[0][tid >> 6] = sum; red[1][tid >> 6] = sq; }
  __syncthreads();
  if (tid == 0) {
    float s = red[0][0] + red[0][1] + red[0][2] + red[0][3];
    float q = red[1][0] + red[1][1] + red[1][2] + red[1][3];
    float mean = s / C, var = q / C - mean * mean;
    mrs[0] = mean; mrs[1] = rsqrtf(var + 1e-5f);
  }
  __syncthreads();
  float mean = mrs[0], rstd = mrs[1];
  for (int c = tid; c < C; c += 256) {
    float y = (xr[c] - mean) * rstd * g[c] + b[c];
    float z = y > 0.f ? y : (__expf(y) - 1.f);
    h1b[(size_t)n * C + c] = f2bf(z);
  }
}

// ------------------------------------------------- LN layer 1: LN(x) -> out fp32
__global__ __launch_bounds__(256) void ln1_kernel(const float* __restrict__ xin,
                                                  const float* __restrict__ g,
                                                  const float* __restrict__ b,
                                                  float* __restrict__ out) {
  const int C = 768;
  int n = blockIdx.x, tid = threadIdx.x;
  __shared__ float red[2][4];
  __shared__ float mrs[2];
  float sum = 0.f, sq = 0.f;
  const float* xr = xin + (size_t)n * C;
  for (int c = tid; c < C; c += 256) {
    float x = xr[c];
    sum += x; sq += x * x;
  }
#pragma unroll
  for (int off = 32; off > 0; off >>= 1) { sum += __shfl_down(sum, off); sq += __shfl_down(sq, off); }
  if ((tid & 63) == 0) { red[0][tid >> 6] = sum; red[1][tid >> 6] = sq; }
  __syncthreads();
  if (tid == 0) {
    float s = red[0][0] + red[0][1] + red[0][2] + red[0][3];
    float q = red[1][0] + red[1][1] + red[1][2] + red[1][3];
    float mean = s / C, var = q / C - mean * mean;
    mrs[0] = mean; mrs[1] = rsqrtf(var + 1e-5f);
  }
  __syncthreads();
  float mean = mrs[0], rstd = mrs[1];
  for (int c = tid; c < C; c += 256)
    out[(size_t)n * C + c] = (xr[c] - mean) * rstd * g[c] + b[c];
}

// ============================================================================
extern "C" void kernel_launch(void* const* d_in, const int* in_sizes, int n_in,
                              void* d_out, int out_size, void* d_ws, size_t ws_size,
                              hipStream_t stream) {
  (void)in_sizes; (void)n_in; (void)out_size; (void)ws_size;
  const float* X    = (const float*)d_in[0];
  const int*   adj  = (const int*)d_in[1];
  const float* ew   = (const float*)d_in[2];
  const float* W0   = (const float*)d_in[3];
  const float* a0   = (const float*)d_in[4];
  const float* W1   = (const float*)d_in[5];
  const float* a1   = (const float*)d_in[6];
  const float* rp0w = (const float*)d_in[7];
  const float* rp0b = (const float*)d_in[8];
  const float* rp1w = (const float*)d_in[9];
  const float* rp1b = (const float*)d_in[10];
  const float* ln0g = (const float*)d_in[11];
  const float* ln0b = (const float*)d_in[12];
  const float* ln1g = (const float*)d_in[13];
  const float* ln1b = (const float*)d_in[14];
  float* out = (float*)d_out;
  char* wsb = (char*)d_ws;

  // ---- workspace layout (bytes): total 146,235,904 (~140 MiB) ----
  // persistent
  constexpr size_t OFF_XBF   = 0;             // [4096][768]   bf16   6291456
  constexpr size_t OFF_W0T   = 6291456;       // [4][512][768] bf16   3145728
  constexpr size_t OFF_W1T   = 9437184;       // [4][768][2048]bf16  12582912
  constexpr size_t OFF_RP0WT = 22020096;      // [2048][768]   bf16   3145728
  constexpr size_t OFF_RP1WT = 25165824;      // [768][2048]   bf16   3145728
  constexpr size_t OFF_WA0   = 28311552;      // [2][4][768]   f32      24576
  constexpr size_t OFF_WA1   = 28336128;      // [2][4][2048]  f32      65536
  constexpr size_t OFF_S0    = 28401664;      // [2][4][4096]  f32     131072
  constexpr size_t OFF_S1    = 28532736;      // [2][4][4096]  f32     131072
  constexpr size_t OFF_C0    = 28663808;      // [4] f32 (pad 256)
  constexpr size_t OFF_C1    = 28664064;      // [4] f32 (pad 256)
  constexpr size_t OFF_L0    = 28664320;      // [4][4096] f32          65536
  constexpr size_t OFF_L1    = 28729856;      // [4][4096] f32          65536
  constexpr size_t OFF_H1B   = 28795392;      // [4096][2048] bf16   16777216
  constexpr size_t D         = 45572608;      // dynamic region
  // layer 0 (D..): WH0 [4][4096][512] bf16 @D; WH0T @D+16777216;
  //                RP0 [4096][2048] f32 @D+33554432
  // layer 1 (D..): WH1 [4][4096][768] bf16 @D; WH1T @D+25165824;
  //                RP1 [4096][768] f32 @D+50331648
  // shared:        P1 [4096][4096] bf16 @D+67108864  (ends 146235904)

  u16*   XBF   = (u16*)(wsb + OFF_XBF);
  u16*   W0T   = (u16*)(wsb + OFF_W0T);
  u16*   W1T   = (u16*)(wsb + OFF_W1T);
  u16*   RP0WT = (u16*)(wsb + OFF_RP0WT);
  u16*   RP1WT = (u16*)(wsb + OFF_RP1WT);
  float* WA0   = (float*)(wsb + OFF_WA0);
  float* WA1   = (float*)(wsb + OFF_WA1);
  float* S0    = (float*)(wsb + OFF_S0);
  float* S1    = (float*)(wsb + OFF_S1);
  float* C0    = (float*)(wsb + OFF_C0);
  float* C1    = (float*)(wsb + OFF_C1);
  float* L0    = (float*)(wsb + OFF_L0);
  float* L1    = (float*)(wsb + OFF_L1);
  u16*   H1B   = (u16*)(wsb + OFF_H1B);
  u16*   WH0   = (u16*)(wsb + D);
  u16*   WH0T  = (u16*)(wsb + D + 16777216);
  float* RP0   = (float*)(wsb + D + 33554432);
  u16*   WH1   = (u16*)(wsb + D);
  u16*   WH1T  = (u16*)(wsb + D + 25165824);
  float* RP1   = (float*)(wsb + D + 50331648);
  u16*   P1    = (u16*)(wsb + D + 67108864);

  // ---- prep ----
  cast_f32_bf16<<<dim3((NN * 768 + 255) / 256), 256, 0, stream>>>(X, XBF, NN * 768);
  transcast_f32<<<dim3(16, 24, 4), 256, 0, stream>>>(W0, W0T, 768, 512);
  transcast_f32<<<dim3(24, 64, 4), 256, 0, stream>>>(W1, W1T, 2048, 768);
  transcast_f32<<<dim3(64, 24, 1), 256, 0, stream>>>(rp0w, RP0WT, 768, 2048);
  transcast_f32<<<dim3(24, 64, 1), 256, 0, stream>>>(rp1w, RP1WT, 2048, 768);

  // ---- layer 0 attention scalars (fp32) ----
  wa_kernel<<<dim3(2 * NHEADS * 768 / 4), 256, 0, stream>>>(W0, a0, WA0, 768, 512);
  s_kernel_f32<<<dim3(2 * NHEADS * NN / 4), 256, 0, stream>>>(X, WA0, S0, 768);
  cmax_kernel<<<dim3(NHEADS), 256, 0, stream>>>(S0, C0);

  // ---- layer 0 GEMMs ----
  // Wh0 = X @ W0  -> [4][4096][512] bf16
  gemm_bt<0><<<dim3(4, 32, 4), 256, 0, stream>>>(XBF, W0T, WH0, nullptr, nullptr,
      768, 512, 0, 0, (size_t)512 * 768, (size_t)NN * 512);
  trans_u16<<<dim3(16, 128, 4), 256, 0, stream>>>(WH0, WH0T, NN, 512);
  // RP0 = X @ rp0w + rp0b  -> [4096][2048] f32
  gemm_bt<1><<<dim3(16, 32, 1), 256, 0, stream>>>(XBF, RP0WT, RP0, nullptr, rp0b,
      768, 2048, 0, 0, 0, 0);
  // per-head: P' then RP0 += elu(P' @ Wh0 / l)
  for (int h = 0; h < NHEADS; h++) {
    pexp_h_kernel<<<dim3(NN), 256, 0, stream>>>(adj, ew, S0, C0, P1, L0, h);
    gemm_bt<2><<<dim3(4, 32, 1), 256, 0, stream>>>(P1, WH0T + (size_t)h * 512 * NN,
        RP0, L0 + (size_t)h * NN, nullptr, NN, 2048, h * 512, 0, 0, 0);
  }
  ln0_kernel<<<dim3(NN), 256, 0, stream>>>(RP0, ln0g, ln0b, H1B);

  // ---- layer 1 attention scalars ----
  wa_kernel<<<dim3(2 * NHEADS * 2048 / 4), 256, 0, stream>>>(W1, a1, WA1, 2048, 768);
  s_kernel_bf16<<<dim3(2 * NHEADS * NN / 4), 256, 0, stream>>>(H1B, WA1, S1, 2048);
  cmax_kernel<<<dim3(NHEADS), 256, 0, stream>>>(S1, C1);

  // ---- layer 1 GEMMs ----
  // Wh1 = h1 @ W1 -> [4][4096][768] bf16
  gemm_bt<0><<<dim3(6, 32, 4), 256, 0, stream>>>(H1B, W1T, WH1, nullptr, nullptr,
      2048, 768, 0, 0, (size_t)768 * 2048, (size_t)NN * 768);
  trans_u16<<<dim3(24, 128, 4), 256, 0, stream>>>(WH1, WH1T, NN, 768);
  // RP1 = h1 @ rp1w + rp1b -> [4096][768] f32
  gemm_bt<1><<<dim3(6, 32, 1), 256, 0, stream>>>(H1B, RP1WT, RP1, nullptr, rp1b,
      2048, 768, 0, 0, 0, 0);
  // per-head: P' then RP1 += 0.25 * P' @ Wh1 / l
  for (int h = 0; h < NHEADS; h++) {
    pexp_h_kernel<<<dim3(NN), 256, 0, stream>>>(adj, ew, S1, C1, P1, L1, h);
    gemm_bt<3><<<dim3(6, 32, 1), 256, 0, stream>>>(P1, WH1T + (size_t)h * 768 * NN,
        RP1, L1 + (size_t)h * NN, nullptr, NN, 768, 0, 0, 0, 0);
  }
  ln1_kernel<<<dim3(NN), 256, 0, stream>>>(RP1, ln1g, ln1b, out);
}

// Round 3
// 965.495 us; speedup vs baseline: 1.6098x; 1.6098x over previous
//
#include <hip/hip_runtime.h>

// ============================================================================
// KnowledgeGraphEncoder: 2-layer dense GAT, N=4096, H=4.
// bf16 MFMA GEMMs (m97-style global_load_lds staging), fp32 softmax logits,
// head-group P materialization sized from ws_size (G=4/2/1).
// ============================================================================

typedef unsigned short u16;
using short8  = __attribute__((ext_vector_type(8))) short;
using float4v = __attribute__((ext_vector_type(4))) float;

#define NN 4096
#define NHEADS 4

__device__ __forceinline__ u16 f2bf(float f) {
  union { float f; unsigned u; } v; v.f = f;
  unsigned u = v.u;
  return (u16)((u + 0x7FFFu + ((u >> 16) & 1u)) >> 16);   // RNE
}
__device__ __forceinline__ float bf2f(u16 x) {
  union { unsigned u; float f; } v; v.u = ((unsigned)x) << 16; return v.f;
}

// async global->LDS, 16B per lane, LDS dest = wave-uniform base + lane*16
__device__ __forceinline__ void async16(const u16* g, u16* l) {
  __builtin_amdgcn_global_load_lds(
      (const __attribute__((address_space(1))) unsigned int*)g,
      (__attribute__((address_space(3))) unsigned int*)l, 16, 0, 0);
}

// ---------------------------------------------------------------- cast fp32->bf16
__global__ __launch_bounds__(256) void cast_f32_bf16(const float* __restrict__ in,
                                                     u16* __restrict__ out, int n) {
  int i = blockIdx.x * 256 + threadIdx.x;
  if (i < n) out[i] = f2bf(in[i]);
}

// ------------------------------------------------- transpose+cast fp32 -> bf16
// in [z][R][C] -> out [z][C][R]
__global__ __launch_bounds__(256) void transcast_f32(const float* __restrict__ in,
                                                     u16* __restrict__ out, int R, int C) {
  __shared__ float t[32][33];
  size_t zoff = (size_t)blockIdx.z * R * C;
  in += zoff; out += zoff;
  int c0 = blockIdx.x * 32, r0 = blockIdx.y * 32;
  int tx = threadIdx.x & 31, ty = threadIdx.x >> 5;
#pragma unroll
  for (int i = 0; i < 32; i += 8)
    t[ty + i][tx] = in[(size_t)(r0 + ty + i) * C + (c0 + tx)];
  __syncthreads();
#pragma unroll
  for (int i = 0; i < 32; i += 8)
    out[(size_t)(c0 + ty + i) * R + (r0 + tx)] = f2bf(t[tx][ty + i]);
}

// ------------------------------------------------- wa[side][h][f] = sum_o W[h][f][o]*a[h][side*O+o]
__global__ __launch_bounds__(256) void wa_kernel(const float* __restrict__ W,
                                                 const float* __restrict__ a,
                                                 float* __restrict__ wa, int F, int O) {
  int gw = blockIdx.x * 4 + (threadIdx.x >> 6);
  int lane = threadIdx.x & 63;
  int total = 2 * NHEADS * F;
  if (gw >= total) return;
  int side = gw / (NHEADS * F);
  int rem = gw - side * NHEADS * F;
  int h = rem / F, f = rem - h * F;
  const float* wrow = W + ((size_t)h * F + f) * O;
  const float* av = a + (size_t)h * 2 * O + (size_t)side * O;
  float s = 0.f;
  for (int o = lane; o < O; o += 64) s += wrow[o] * av[o];
#pragma unroll
  for (int off = 32; off > 0; off >>= 1) s += __shfl_down(s, off);
  if (lane == 0) wa[gw] = s;
}

// ------------------------------------------------- s[side][h][n] from fp32 X
__global__ __launch_bounds__(256) void s_kernel_f32(const float* __restrict__ X,
                                                    const float* __restrict__ wa,
                                                    float* __restrict__ sout, int F) {
  int gw = blockIdx.x * 4 + (threadIdx.x >> 6);
  int lane = threadIdx.x & 63;
  if (gw >= 2 * NHEADS * NN) return;
  int n = gw & (NN - 1);
  int sh = gw >> 12;
  const float* x = X + (size_t)n * F;
  const float* w = wa + (size_t)sh * F;
  float s = 0.f;
  for (int f = lane; f < F; f += 64) s += x[f] * w[f];
#pragma unroll
  for (int off = 32; off > 0; off >>= 1) s += __shfl_down(s, off);
  if (lane == 0) sout[gw] = s;
}

// ------------------------------------------------- s[side][h][n] from bf16 X
__global__ __launch_bounds__(256) void s_kernel_bf16(const u16* __restrict__ X,
                                                     const float* __restrict__ wa,
                                                     float* __restrict__ sout, int F) {
  int gw = blockIdx.x * 4 + (threadIdx.x >> 6);
  int lane = threadIdx.x & 63;
  if (gw >= 2 * NHEADS * NN) return;
  int n = gw & (NN - 1);
  int sh = gw >> 12;
  const u16* x = X + (size_t)n * F;
  const float* w = wa + (size_t)sh * F;
  float s = 0.f;
  for (int f = lane; f < F; f += 64) s += bf2f(x[f]) * w[f];
#pragma unroll
  for (int off = 32; off > 0; off >>= 1) s += __shfl_down(s, off);
  if (lane == 0) sout[gw] = s;
}

// ------------------------------------------------- C[h] = max(0, max_i ssrc + max_j sdst)
__global__ __launch_bounds__(256) void cmax_kernel(const float* __restrict__ s,
                                                   float* __restrict__ Cout) {
  int h = blockIdx.x, tid = threadIdx.x;
  const float* ss = s + (size_t)h * NN;
  const float* sd = s + (size_t)(NHEADS + h) * NN;
  float ms = -1e30f, md = -1e30f;
  for (int i = tid; i < NN; i += 256) { ms = fmaxf(ms, ss[i]); md = fmaxf(md, sd[i]); }
  __shared__ float r1[4], r2[4];
#pragma unroll
  for (int off = 32; off > 0; off >>= 1) {
    ms = fmaxf(ms, __shfl_down(ms, off));
    md = fmaxf(md, __shfl_down(md, off));
  }
  if ((tid & 63) == 0) { r1[tid >> 6] = ms; r2[tid >> 6] = md; }
  __syncthreads();
  if (tid == 0) {
    ms = fmaxf(fmaxf(r1[0], r1[1]), fmaxf(r1[2], r1[3]));
    md = fmaxf(fmaxf(r2[0], r2[1]), fmaxf(r2[2], r2[3]));
    Cout[h] = fmaxf(ms + md, 0.0f);
  }
}

// ------------------------------------------------- G-head P' = exp(att - C[h]) bf16, l = rowsum
template <int G>
__global__ __launch_bounds__(256) void pexp_g_kernel(const int* __restrict__ adj,
                                                     const float* __restrict__ ew,
                                                     const float* __restrict__ s,
                                                     const float* __restrict__ Cmax,
                                                     u16* __restrict__ P,
                                                     float* __restrict__ L, int hb) {
  int i = blockIdx.x, tid = threadIdx.x;
  float sr[G], Cv[G], lacc[G];
#pragma unroll
  for (int z = 0; z < G; z++) {
    sr[z] = s[(size_t)(hb + z) * NN + i];
    Cv[z] = Cmax[hb + z];
    lacc[z] = 0.f;
  }
  const int4* arow = (const int4*)(adj + (size_t)i * NN);
  const float4* wrow = (const float4*)(ew + (size_t)i * NN);
  for (int jv = tid; jv < NN / 4; jv += 256) {
    int4 a = arow[jv];
    float4 w = wrow[jv];
    int j0 = jv * 4;
    float we[4];
    we[0] = w.x; we[1] = w.y; we[2] = w.z; we[3] = w.w;
    bool m[4];
    m[0] = (a.x != 0) || (j0 + 0 == i);
    m[1] = (a.y != 0) || (j0 + 1 == i);
    m[2] = (a.z != 0) || (j0 + 2 == i);
    m[3] = (a.w != 0) || (j0 + 3 == i);
#pragma unroll
    for (int z = 0; z < G; z++) {
      const float4 sd4 = *(const float4*)(s + (size_t)(NHEADS + hb + z) * NN + j0);
      float sd[4]; sd[0] = sd4.x; sd[1] = sd4.y; sd[2] = sd4.z; sd[3] = sd4.w;
      unsigned long long pk = 0;
#pragma unroll
      for (int k = 0; k < 4; k++) {
        float x = sr[z] + sd[k];
        float e = x > 0.f ? x : 0.2f * x;
        float v = (m[k] ? e : -9e15f) * we[k];
        float p = __expf(v - Cv[z]);
        pk |= ((unsigned long long)f2bf(p)) << (16 * k);
        lacc[z] += p;
      }
      *(unsigned long long*)(P + ((size_t)z * NN + i) * NN + j0) = pk;
    }
  }
  __shared__ float red[G][4];
#pragma unroll
  for (int z = 0; z < G; z++) {
    float r = lacc[z];
#pragma unroll
    for (int off = 32; off > 0; off >>= 1) r += __shfl_down(r, off);
    if ((tid & 63) == 0) red[z][tid >> 6] = r;
  }
  __syncthreads();
  if (tid < G)
    L[(size_t)(hb + tid) * NN + i] = red[tid][0] + red[tid][1] + red[tid][2] + red[tid][3];
}

// ------------------------------------------------- 128x128 bf16 MFMA GEMM, B^T input
// m97-style: global_load_lds dwordx4 staging, 2-barrier K-loop.
// MODE 0: bf16 store                  MODE 4: bf16 store TRANSPOSED (ldc = row stride of C^T)
// MODE 1: fp32 store of v + bias[col]
// MODE 2: C[idx] += elu(v / l[row])   (layer-0 attn; coloff = base + z*step, disjoint cols)
// MODE 3: atomicAdd(C[idx], 0.25*v/l) (layer-1 attn; heads race -> atomic)
template <int MODE>
__global__ __launch_bounds__(256) void gemm_bt(const u16* __restrict__ A,
                                               const u16* __restrict__ Bt,
                                               void* __restrict__ Cout,
                                               const float* __restrict__ rowscale,
                                               const float* __restrict__ bias,
                                               int K, int ldc, int coloff_base, int coloff_step,
                                               size_t aStride, size_t bStride,
                                               size_t cStride, size_t rsStride) {
  int h = blockIdx.z;
  const u16* Ab = A + (size_t)h * aStride;
  const u16* Bb = Bt + (size_t)h * bStride;
  const float* rs = rowscale + (size_t)h * rsStride;
  int row0 = blockIdx.y * 128;
  int col0 = blockIdx.x * 128;
  int coloff = coloff_base + h * coloff_step;

  __shared__ u16 ldsA[128 * 32];
  __shared__ u16 ldsB[128 * 32];

  int tid = threadIdx.x;
  int wave = tid >> 6, lane = tid & 63;
  int wm = wave >> 1, wn = wave & 1;
  int lm = lane & 15, kq = (lane >> 4) * 8;

  const u16* aPtr = Ab + (size_t)(row0 + (tid >> 2)) * K + ((tid & 3) * 8);
  const u16* bPtr = Bb + (size_t)(col0 + (tid >> 2)) * K + ((tid & 3) * 8);
  u16* ldsAw = &ldsA[wave * 512];
  u16* ldsBw = &ldsB[wave * 512];
  const size_t rowStep = (size_t)64 * K;

  float4v acc[4][4] = {};

  for (int k0 = 0; k0 < K; k0 += 32) {
    __syncthreads();                      // all waves done reading previous tile
    async16(aPtr + k0,           ldsAw);
    async16(aPtr + k0 + rowStep, ldsAw + 2048);
    async16(bPtr + k0,           ldsBw);
    async16(bPtr + k0 + rowStep, ldsBw + 2048);
    __syncthreads();                      // vmcnt(0) drain before barrier -> tile ready
    short8 af[4], bf[4];
#pragma unroll
    for (int s = 0; s < 4; s++) {
      af[s] = *(const short8*)(&ldsA[(wm * 64 + s * 16 + lm) * 32 + kq]);
      bf[s] = *(const short8*)(&ldsB[(wn * 64 + s * 16 + lm) * 32 + kq]);
    }
#pragma unroll
    for (int i = 0; i < 4; i++)
#pragma unroll
      for (int j = 0; j < 4; j++)
        acc[i][j] = __builtin_amdgcn_mfma_f32_16x16x32_bf16(af[i], bf[j], acc[i][j], 0, 0, 0);
  }

#pragma unroll
  for (int i = 0; i < 4; i++) {
#pragma unroll
    for (int j = 0; j < 4; j++) {
#pragma unroll
      for (int r = 0; r < 4; r++) {
        int grow = row0 + wm * 64 + i * 16 + (lane >> 4) * 4 + r;
        int gcol = col0 + wn * 64 + j * 16 + lm;
        float v = acc[i][j][r];
        if constexpr (MODE == 0) {
          ((u16*)Cout)[(size_t)h * cStride + (size_t)grow * ldc + coloff + gcol] = f2bf(v);
        } else if constexpr (MODE == 4) {
          ((u16*)Cout)[(size_t)h * cStride + (size_t)(coloff + gcol) * ldc + grow] = f2bf(v);
        } else if constexpr (MODE == 1) {
          ((float*)Cout)[(size_t)grow * ldc + coloff + gcol] = v + bias[coloff + gcol];
        } else if constexpr (MODE == 2) {
          v *= (1.0f / rs[grow]);
          v = v > 0.f ? v : (__expf(v) - 1.f);
          ((float*)Cout)[(size_t)grow * ldc + coloff + gcol] += v;
        } else {
          v *= (1.0f / rs[grow]);
          atomicAdd(&((float*)Cout)[(size_t)grow * ldc + coloff + gcol], 0.25f * v);
        }
      }
    }
  }
}

// ------------------------------------------------- LN layer 0: LN(x) -> elu -> bf16
__global__ __launch_bounds__(256) void ln0_kernel(const float* __restrict__ xin,
                                                  const float* __restrict__ g,
                                                  const float* __restrict__ b,
                                                  u16* __restrict__ h1b) {
  const int C = 2048;
  int n = blockIdx.x, tid = threadIdx.x;
  __shared__ float red[2][4];
  __shared__ float mrs[2];
  float sum = 0.f, sq = 0.f;
  const float* xr = xin + (size_t)n * C;
  for (int c = tid; c < C; c += 256) {
    float x = xr[c];
    sum += x; sq += x * x;
  }
#pragma unroll
  for (int off = 32; off > 0; off >>= 1) { sum += __shfl_down(sum, off); sq += __shfl_down(sq, off); }
  if ((tid & 63) == 0) { red[0][tid >> 6] = sum; red[1][tid >> 6] = sq; }
  __syncthreads();
  if (tid == 0) {
    float s = red[0][0] + red[0][1] + red[0][2] + red[0][3];
    float q = red[1][0] + red[1][1] + red[1][2] + red[1][3];
    float mean = s / C, var = q / C - mean * mean;
    mrs[0] = mean; mrs[1] = rsqrtf(var + 1e-5f);
  }
  __syncthreads();
  float mean = mrs[0], rstd = mrs[1];
  for (int c = tid; c < C; c += 256) {
    float y = (xr[c] - mean) * rstd * g[c] + b[c];
    float z = y > 0.f ? y : (__expf(y) - 1.f);
    h1b[(size_t)n * C + c] = f2bf(z);
  }
}

// ------------------------------------------------- LN layer 1: LN(x) -> out fp32
__global__ __launch_bounds__(256) void ln1_kernel(const float* __restrict__ xin,
                                                  const float* __restrict__ g,
                                                  const float* __restrict__ b,
                                                  float* __restrict__ out) {
  const int C = 768;
  int n = blockIdx.x, tid = threadIdx.x;
  __shared__ float red[2][4];
  __shared__ float mrs[2];
  float sum = 0.f, sq = 0.f;
  const float* xr = xin + (size_t)n * C;
  for (int c = tid; c < C; c += 256) {
    float x = xr[c];
    sum += x; sq += x * x;
  }
#pragma unroll
  for (int off = 32; off > 0; off >>= 1) { sum += __shfl_down(sum, off); sq += __shfl_down(sq, off); }
  if ((tid & 63) == 0) { red[0][tid >> 6] = sum; red[1][tid >> 6] = sq; }
  __syncthreads();
  if (tid == 0) {
    float s = red[0][0] + red[0][1] + red[0][2] + red[0][3];
    float q = red[1][0] + red[1][1] + red[1][2] + red[1][3];
    float mean = s / C, var = q / C - mean * mean;
    mrs[0] = mean; mrs[1] = rsqrtf(var + 1e-5f);
  }
  __syncthreads();
  float mean = mrs[0], rstd = mrs[1];
  for (int c = tid; c < C; c += 256)
    out[(size_t)n * C + c] = (xr[c] - mean) * rstd * g[c] + b[c];
}

// ============================================================================
extern "C" void kernel_launch(void* const* d_in, const int* in_sizes, int n_in,
                              void* d_out, int out_size, void* d_ws, size_t ws_size,
                              hipStream_t stream) {
  (void)in_sizes; (void)n_in; (void)out_size;
  const float* X    = (const float*)d_in[0];
  const int*   adj  = (const int*)d_in[1];
  const float* ew   = (const float*)d_in[2];
  const float* W0   = (const float*)d_in[3];
  const float* a0   = (const float*)d_in[4];
  const float* W1   = (const float*)d_in[5];
  const float* a1   = (const float*)d_in[6];
  const float* rp0w = (const float*)d_in[7];
  const float* rp0b = (const float*)d_in[8];
  const float* rp1w = (const float*)d_in[9];
  const float* rp1b = (const float*)d_in[10];
  const float* ln0g = (const float*)d_in[11];
  const float* ln0b = (const float*)d_in[12];
  const float* ln1g = (const float*)d_in[13];
  const float* ln1b = (const float*)d_in[14];
  float* out = (float*)d_out;
  char* wsb = (char*)d_ws;

  // ---- workspace layout (bytes) ----
  constexpr size_t OFF_XBF   = 0;             // [4096][768]   bf16   6291456
  constexpr size_t OFF_W0T   = 6291456;       // [4][512][768] bf16   3145728
  constexpr size_t OFF_W1T   = 9437184;       // [4][768][2048]bf16  12582912
  constexpr size_t OFF_RP0WT = 22020096;      // [2048][768]   bf16   3145728
  constexpr size_t OFF_RP1WT = 25165824;      // [768][2048]   bf16   3145728
  constexpr size_t OFF_WA0   = 28311552;
  constexpr size_t OFF_WA1   = 28336128;
  constexpr size_t OFF_S0    = 28401664;
  constexpr size_t OFF_S1    = 28532736;
  constexpr size_t OFF_C0    = 28663808;
  constexpr size_t OFF_C1    = 28664064;
  constexpr size_t OFF_L0    = 28664320;
  constexpr size_t OFF_L1    = 28729856;
  constexpr size_t OFF_H1B   = 28795392;      // [4096][2048] bf16   16777216
  constexpr size_t D         = 45572608;      // dynamic region
  // layer0: WH0T [4][512][4096] bf16 @D (16777216); RP0 [4096][2048] f32 @D+16777216 (33554432)
  // layer1: WH1T [4][768][4096] bf16 @D (25165824); RP1 [4096][768] f32 @D+25165824 (12582912)
  constexpr size_t PD        = D + 50331648;  // P region @ 95904256
  constexpr size_t PN        = (size_t)NN * NN * 2;  // 33554432 per head

  u16*   XBF   = (u16*)(wsb + OFF_XBF);
  u16*   W0T   = (u16*)(wsb + OFF_W0T);
  u16*   W1T   = (u16*)(wsb + OFF_W1T);
  u16*   RP0WT = (u16*)(wsb + OFF_RP0WT);
  u16*   RP1WT = (u16*)(wsb + OFF_RP1WT);
  float* WA0   = (float*)(wsb + OFF_WA0);
  float* WA1   = (float*)(wsb + OFF_WA1);
  float* S0    = (float*)(wsb + OFF_S0);
  float* S1    = (float*)(wsb + OFF_S1);
  float* C0    = (float*)(wsb + OFF_C0);
  float* C1    = (float*)(wsb + OFF_C1);
  float* L0    = (float*)(wsb + OFF_L0);
  float* L1    = (float*)(wsb + OFF_L1);
  u16*   H1B   = (u16*)(wsb + OFF_H1B);
  u16*   WH0T  = (u16*)(wsb + D);
  float* RP0   = (float*)(wsb + D + 16777216);
  u16*   WH1T  = (u16*)(wsb + D);
  float* RP1   = (float*)(wsb + D + 25165824);
  u16*   P     = (u16*)(wsb + PD);

  // head-group size from available workspace (ws_size constant per session).
  // need(G) = PD + G*PN: G=4 -> 230,121,984; G=2 -> 163,013,120; G=1 -> 129,458,688 (always fits: >=146M proven)
  const int G = (ws_size >= PD + 4 * PN) ? 4 : (ws_size >= PD + 2 * PN) ? 2 : 1;

  // ---- prep ----
  cast_f32_bf16<<<dim3((NN * 768 + 255) / 256), 256, 0, stream>>>(X, XBF, NN * 768);
  transcast_f32<<<dim3(16, 24, 4), 256, 0, stream>>>(W0, W0T, 768, 512);
  transcast_f32<<<dim3(24, 64, 4), 256, 0, stream>>>(W1, W1T, 2048, 768);
  transcast_f32<<<dim3(64, 24, 1), 256, 0, stream>>>(rp0w, RP0WT, 768, 2048);
  transcast_f32<<<dim3(24, 64, 1), 256, 0, stream>>>(rp1w, RP1WT, 2048, 768);

  // ---- layer 0 attention scalars (fp32 exact) ----
  wa_kernel<<<dim3(2 * NHEADS * 768 / 4), 256, 0, stream>>>(W0, a0, WA0, 768, 512);
  s_kernel_f32<<<dim3(2 * NHEADS * NN / 4), 256, 0, stream>>>(X, WA0, S0, 768);
  cmax_kernel<<<dim3(NHEADS), 256, 0, stream>>>(S0, C0);

  // ---- layer 0 GEMMs ----
  // Wh0^T[h][o][n] = (X @ W0[h])^T  (transposed bf16 store, kills trans_u16)
  gemm_bt<4><<<dim3(4, 32, 4), 256, 0, stream>>>(XBF, W0T, WH0T, L0, nullptr,
      768, NN, 0, 0, 0, (size_t)512 * 768, (size_t)512 * NN, 0);
  // RP0 = X @ rp0w + rp0b
  gemm_bt<1><<<dim3(16, 32, 1), 256, 0, stream>>>(XBF, RP0WT, RP0, L0, rp0b,
      768, 2048, 0, 0, 0, 0, 0, 0);
  // per head-group: P' then RP0[:, h*512:(h+1)*512] += elu(P' @ Wh0 / l)
  for (int g = 0; g < NHEADS; g += G) {
    if (G == 4)      pexp_g_kernel<4><<<dim3(NN), 256, 0, stream>>>(adj, ew, S0, C0, P, L0, g);
    else if (G == 2) pexp_g_kernel<2><<<dim3(NN), 256, 0, stream>>>(adj, ew, S0, C0, P, L0, g);
    else             pexp_g_kernel<1><<<dim3(NN), 256, 0, stream>>>(adj, ew, S0, C0, P, L0, g);
    gemm_bt<2><<<dim3(4, 32, G), 256, 0, stream>>>(P, WH0T + (size_t)g * 512 * NN,
        RP0, L0 + (size_t)g * NN, nullptr,
        NN, 2048, g * 512, 512, (size_t)NN * NN, (size_t)512 * NN, 0, NN);
  }
  ln0_kernel<<<dim3(NN), 256, 0, stream>>>(RP0, ln0g, ln0b, H1B);

  // ---- layer 1 attention scalars ----
  wa_kernel<<<dim3(2 * NHEADS * 2048 / 4), 256, 0, stream>>>(W1, a1, WA1, 2048, 768);
  s_kernel_bf16<<<dim3(2 * NHEADS * NN / 4), 256, 0, stream>>>(H1B, WA1, S1, 2048);
  cmax_kernel<<<dim3(NHEADS), 256, 0, stream>>>(S1, C1);

  // ---- layer 1 GEMMs ----
  // Wh1^T[h][o][n] = (h1 @ W1[h])^T
  gemm_bt<4><<<dim3(6, 32, 4), 256, 0, stream>>>(H1B, W1T, WH1T, L1, nullptr,
      2048, NN, 0, 0, 0, (size_t)768 * 2048, (size_t)768 * NN, 0);
  // RP1 = h1 @ rp1w + rp1b
  gemm_bt<1><<<dim3(6, 32, 1), 256, 0, stream>>>(H1B, RP1WT, RP1, L1, rp1b,
      2048, 768, 0, 0, 0, 0, 0, 0);
  // per head-group: P' then RP1 += 0.25 * P' @ Wh1 / l  (atomic across heads)
  for (int g = 0; g < NHEADS; g += G) {
    if (G == 4)      pexp_g_kernel<4><<<dim3(NN), 256, 0, stream>>>(adj, ew, S1, C1, P, L1, g);
    else if (G == 2) pexp_g_kernel<2><<<dim3(NN), 256, 0, stream>>>(adj, ew, S1, C1, P, L1, g);
    else             pexp_g_kernel<1><<<dim3(NN), 256, 0, stream>>>(adj, ew, S1, C1, P, L1, g);
    gemm_bt<3><<<dim3(6, 32, G), 256, 0, stream>>>(P, WH1T + (size_t)g * 768 * NN,
        RP1, L1 + (size_t)g * NN, nullptr,
        NN, 768, 0, 0, (size_t)NN * NN, (size_t)768 * NN, 0, NN);
  }
  ln1_kernel<<<dim3(NN), 256, 0, stream>>>(RP1, ln1g, ln1b, out);
}

// Round 4
// 913.365 us; speedup vs baseline: 1.7017x; 1.0571x over previous
//
#include <hip/hip_runtime.h>

// ============================================================================
// KnowledgeGraphEncoder: 2-layer dense GAT, N=4096, H=4.
// bf16 MFMA for dense projections; fp8(e4m3) MFMA for the P.Wh attention GEMMs
// (P produced with per-row softmax max -> p in [~0,1], fp8-safe).
// fp32 softmax logits throughout. ws usage ~163 MB (<=230 MB proven available).
// ============================================================================

typedef unsigned short u16;
typedef unsigned char u8;
using short8  = __attribute__((ext_vector_type(8))) short;
using float4v = __attribute__((ext_vector_type(4))) float;

#define NN 4096
#define NHEADS 4

__device__ __forceinline__ u16 f2bf(float f) {
  union { float f; unsigned u; } v; v.f = f;
  unsigned u = v.u;
  return (u16)((u + 0x7FFFu + ((u >> 16) & 1u)) >> 16);   // RNE
}
__device__ __forceinline__ float bf2f(u16 x) {
  union { unsigned u; float f; } v; v.u = ((unsigned)x) << 16; return v.f;
}
// pack 4 floats -> 4 fp8 e4m3 bytes (HW cvt, OCP on gfx950)
__device__ __forceinline__ unsigned pk_fp8x4(float a, float b, float c, float d) {
  int lo = __builtin_amdgcn_cvt_pk_fp8_f32(a, b, 0, false);
  return (unsigned)__builtin_amdgcn_cvt_pk_fp8_f32(c, d, lo, true);
}

// async global->LDS, 16B per lane, LDS dest = wave-uniform base + lane*16
__device__ __forceinline__ void async16(const void* g, void* l) {
  __builtin_amdgcn_global_load_lds(
      (const __attribute__((address_space(1))) unsigned int*)g,
      (__attribute__((address_space(3))) unsigned int*)l, 16, 0, 0);
}

// ---------------------------------------------------------------- cast fp32->bf16
__global__ __launch_bounds__(256) void cast_f32_bf16(const float* __restrict__ in,
                                                     u16* __restrict__ out, int n) {
  int i = blockIdx.x * 256 + threadIdx.x;
  if (i < n) out[i] = f2bf(in[i]);
}

// ------------------------------------------------- transpose+cast fp32 -> bf16
__global__ __launch_bounds__(256) void transcast_f32(const float* __restrict__ in,
                                                     u16* __restrict__ out, int R, int C) {
  __shared__ float t[32][33];
  size_t zoff = (size_t)blockIdx.z * R * C;
  in += zoff; out += zoff;
  int c0 = blockIdx.x * 32, r0 = blockIdx.y * 32;
  int tx = threadIdx.x & 31, ty = threadIdx.x >> 5;
#pragma unroll
  for (int i = 0; i < 32; i += 8)
    t[ty + i][tx] = in[(size_t)(r0 + ty + i) * C + (c0 + tx)];
  __syncthreads();
#pragma unroll
  for (int i = 0; i < 32; i += 8)
    out[(size_t)(c0 + ty + i) * R + (r0 + tx)] = f2bf(t[tx][ty + i]);
}

// ------------------------------------------------- wa[side][h][f] = sum_o W[h][f][o]*a[h][side*O+o]
__global__ __launch_bounds__(256) void wa_kernel(const float* __restrict__ W,
                                                 const float* __restrict__ a,
                                                 float* __restrict__ wa, int F, int O) {
  int gw = blockIdx.x * 4 + (threadIdx.x >> 6);
  int lane = threadIdx.x & 63;
  int total = 2 * NHEADS * F;
  if (gw >= total) return;
  int side = gw / (NHEADS * F);
  int rem = gw - side * NHEADS * F;
  int h = rem / F, f = rem - h * F;
  const float* wrow = W + ((size_t)h * F + f) * O;
  const float* av = a + (size_t)h * 2 * O + (size_t)side * O;
  float s = 0.f;
  for (int o = lane; o < O; o += 64) s += wrow[o] * av[o];
#pragma unroll
  for (int off = 32; off > 0; off >>= 1) s += __shfl_down(s, off);
  if (lane == 0) wa[gw] = s;
}

// ------------------------------------------------- s[side][h][n] from fp32 X
__global__ __launch_bounds__(256) void s_kernel_f32(const float* __restrict__ X,
                                                    const float* __restrict__ wa,
                                                    float* __restrict__ sout, int F) {
  int gw = blockIdx.x * 4 + (threadIdx.x >> 6);
  int lane = threadIdx.x & 63;
  if (gw >= 2 * NHEADS * NN) return;
  int n = gw & (NN - 1);
  int sh = gw >> 12;
  const float* x = X + (size_t)n * F;
  const float* w = wa + (size_t)sh * F;
  float s = 0.f;
  for (int f = lane; f < F; f += 64) s += x[f] * w[f];
#pragma unroll
  for (int off = 32; off > 0; off >>= 1) s += __shfl_down(s, off);
  if (lane == 0) sout[gw] = s;
}

// ------------------------------------------------- s[side][h][n] from bf16 X
__global__ __launch_bounds__(256) void s_kernel_bf16(const u16* __restrict__ X,
                                                     const float* __restrict__ wa,
                                                     float* __restrict__ sout, int F) {
  int gw = blockIdx.x * 4 + (threadIdx.x >> 6);
  int lane = threadIdx.x & 63;
  if (gw >= 2 * NHEADS * NN) return;
  int n = gw & (NN - 1);
  int sh = gw >> 12;
  const u16* x = X + (size_t)n * F;
  const float* w = wa + (size_t)sh * F;
  float s = 0.f;
  for (int f = lane; f < F; f += 64) s += bf2f(x[f]) * w[f];
#pragma unroll
  for (int off = 32; off > 0; off >>= 1) s += __shfl_down(s, off);
  if (lane == 0) sout[gw] = s;
}

// ------------------------------------------------- G-head P' = exp(v - rowmax) fp8, l = rowsum (fp32)
// Two passes: (1) compute v -> LDS, track row max; (2) exp, pack fp8, rowsum.
template <int G>
__global__ __launch_bounds__(256) void pexp_g_kernel(const int* __restrict__ adj,
                                                     const float* __restrict__ ew,
                                                     const float* __restrict__ s,
                                                     u8* __restrict__ P,
                                                     float* __restrict__ L, int hb) {
  __shared__ float vbuf[G][NN];
  __shared__ float mred[G][4];
  __shared__ float lred[G][4];
  __shared__ float mrow[G];
  int i = blockIdx.x, tid = threadIdx.x;
  float sr[G], mx[G], lacc[G];
#pragma unroll
  for (int z = 0; z < G; z++) {
    sr[z] = s[(size_t)(hb + z) * NN + i];
    mx[z] = -3e38f;
    lacc[z] = 0.f;
  }
  const int4* arow = (const int4*)(adj + (size_t)i * NN);
  const float4* wrow = (const float4*)(ew + (size_t)i * NN);
  // pass 1: v -> LDS, row max
  for (int jv = tid; jv < NN / 4; jv += 256) {
    int4 a = arow[jv];
    float4 w = wrow[jv];
    int j0 = jv * 4;
    float we[4]; we[0] = w.x; we[1] = w.y; we[2] = w.z; we[3] = w.w;
    bool m[4];
    m[0] = (a.x != 0) || (j0 + 0 == i);
    m[1] = (a.y != 0) || (j0 + 1 == i);
    m[2] = (a.z != 0) || (j0 + 2 == i);
    m[3] = (a.w != 0) || (j0 + 3 == i);
#pragma unroll
    for (int z = 0; z < G; z++) {
      const float4 sd4 = *(const float4*)(s + (size_t)(NHEADS + hb + z) * NN + j0);
      float sd[4]; sd[0] = sd4.x; sd[1] = sd4.y; sd[2] = sd4.z; sd[3] = sd4.w;
      float4 vv;
      float* vp = (float*)&vv;
#pragma unroll
      for (int k = 0; k < 4; k++) {
        float x = sr[z] + sd[k];
        float e = x > 0.f ? x : 0.2f * x;
        float v = (m[k] ? e : -9e15f) * we[k];
        vp[k] = v;
        mx[z] = fmaxf(mx[z], v);
      }
      *(float4*)(&vbuf[z][j0]) = vv;
    }
  }
#pragma unroll
  for (int z = 0; z < G; z++) {
    float r = mx[z];
#pragma unroll
    for (int off = 32; off > 0; off >>= 1) r = fmaxf(r, __shfl_down(r, off));
    if ((tid & 63) == 0) mred[z][tid >> 6] = r;
  }
  __syncthreads();
  if (tid < G)
    mrow[tid] = fmaxf(fmaxf(mred[tid][0], mred[tid][1]), fmaxf(mred[tid][2], mred[tid][3]));
  __syncthreads();
  float mv[G];
#pragma unroll
  for (int z = 0; z < G; z++) mv[z] = mrow[z];
  // pass 2: p = exp(v - m), fp8 pack, rowsum
  for (int jv = tid; jv < NN / 4; jv += 256) {
    int j0 = jv * 4;
#pragma unroll
    for (int z = 0; z < G; z++) {
      float4 vv = *(const float4*)(&vbuf[z][j0]);
      float p0 = __expf(vv.x - mv[z]);
      float p1 = __expf(vv.y - mv[z]);
      float p2 = __expf(vv.z - mv[z]);
      float p3 = __expf(vv.w - mv[z]);
      lacc[z] += (p0 + p1) + (p2 + p3);
      *(unsigned*)(P + ((size_t)z * NN + i) * NN + j0) = pk_fp8x4(p0, p1, p2, p3);
    }
  }
#pragma unroll
  for (int z = 0; z < G; z++) {
    float r = lacc[z];
#pragma unroll
    for (int off = 32; off > 0; off >>= 1) r += __shfl_down(r, off);
    if ((tid & 63) == 0) lred[z][tid >> 6] = r;
  }
  __syncthreads();
  if (tid < G)
    L[(size_t)(hb + tid) * NN + i] = lred[tid][0] + lred[tid][1] + lred[tid][2] + lred[tid][3];
}

// ------------------------------------------------- 128x128 bf16 MFMA GEMM, B^T input
// MODE 0: bf16 store          MODE 4: fp8 store TRANSPOSED (packed dword, ldc=C^T row stride)
// MODE 1: fp32 store of v + bias[col]
template <int MODE>
__global__ __launch_bounds__(256) void gemm_bt(const u16* __restrict__ A,
                                               const u16* __restrict__ Bt,
                                               void* __restrict__ Cout,
                                               const float* __restrict__ bias,
                                               int K, int ldc, int coloff_base, int coloff_step,
                                               size_t aStride, size_t bStride,
                                               size_t cStride) {
  int h = blockIdx.z;
  const u16* Ab = A + (size_t)h * aStride;
  const u16* Bb = Bt + (size_t)h * bStride;
  int row0 = blockIdx.y * 128;
  int col0 = blockIdx.x * 128;
  int coloff = coloff_base + h * coloff_step;

  __shared__ u16 ldsA[128 * 32];
  __shared__ u16 ldsB[128 * 32];

  int tid = threadIdx.x;
  int wave = tid >> 6, lane = tid & 63;
  int wm = wave >> 1, wn = wave & 1;
  int lm = lane & 15, kq = (lane >> 4) * 8;

  const u16* aPtr = Ab + (size_t)(row0 + (tid >> 2)) * K + ((tid & 3) * 8);
  const u16* bPtr = Bb + (size_t)(col0 + (tid >> 2)) * K + ((tid & 3) * 8);
  u16* ldsAw = &ldsA[wave * 512];
  u16* ldsBw = &ldsB[wave * 512];
  const size_t rowStep = (size_t)64 * K;

  float4v acc[4][4] = {};

  for (int k0 = 0; k0 < K; k0 += 32) {
    __syncthreads();
    async16(aPtr + k0,           ldsAw);
    async16(aPtr + k0 + rowStep, ldsAw + 2048);
    async16(bPtr + k0,           ldsBw);
    async16(bPtr + k0 + rowStep, ldsBw + 2048);
    __syncthreads();
    short8 af[4], bf[4];
#pragma unroll
    for (int s = 0; s < 4; s++) {
      af[s] = *(const short8*)(&ldsA[(wm * 64 + s * 16 + lm) * 32 + kq]);
      bf[s] = *(const short8*)(&ldsB[(wn * 64 + s * 16 + lm) * 32 + kq]);
    }
#pragma unroll
    for (int i = 0; i < 4; i++)
#pragma unroll
      for (int j = 0; j < 4; j++)
        acc[i][j] = __builtin_amdgcn_mfma_f32_16x16x32_bf16(af[i], bf[j], acc[i][j], 0, 0, 0);
  }

#pragma unroll
  for (int i = 0; i < 4; i++) {
#pragma unroll
    for (int j = 0; j < 4; j++) {
      int grow0 = row0 + wm * 64 + i * 16 + (lane >> 4) * 4;
      int gcol = col0 + wn * 64 + j * 16 + lm;
      if constexpr (MODE == 4) {
        unsigned pk = pk_fp8x4(acc[i][j][0], acc[i][j][1], acc[i][j][2], acc[i][j][3]);
        *(unsigned*)&((u8*)Cout)[(size_t)h * cStride + (size_t)(coloff + gcol) * ldc + grow0] = pk;
      } else {
#pragma unroll
        for (int r = 0; r < 4; r++) {
          int grow = grow0 + r;
          float v = acc[i][j][r];
          size_t idx = (size_t)grow * ldc + coloff + gcol;
          if constexpr (MODE == 0) {
            ((u16*)Cout)[(size_t)h * cStride + idx] = f2bf(v);
          } else {
            ((float*)Cout)[idx] = v + bias[coloff + gcol];
          }
        }
      }
    }
  }
}

// ------------------------------------------------- 128x128 fp8 MFMA GEMM, B^T input (attention)
// MODE 2: C[idx] += elu(v / l[row])   (layer-0 attn; coloff = base + z*step, disjoint cols)
// MODE 3: atomicAdd(C[idx], 0.25*v/l) (layer-1 attn; heads race -> atomic)
template <int MODE>
__global__ __launch_bounds__(256) void gemm_fp8(const u8* __restrict__ A,
                                                const u8* __restrict__ Bt,
                                                float* __restrict__ Cout,
                                                const float* __restrict__ rowscale,
                                                int K, int ldc, int coloff_base, int coloff_step,
                                                size_t aStride, size_t bStride,
                                                size_t rsStride) {
  int h = blockIdx.z;
  const u8* Ab = A + (size_t)h * aStride;
  const u8* Bb = Bt + (size_t)h * bStride;
  const float* rs = rowscale + (size_t)h * rsStride;
  int row0 = blockIdx.y * 128;
  int col0 = blockIdx.x * 128;
  int coloff = coloff_base + h * coloff_step;

  __shared__ u8 ldsA[128 * 32];
  __shared__ u8 ldsB[128 * 32];

  int tid = threadIdx.x;
  int wave = tid >> 6, lane = tid & 63;
  int wm = wave >> 1, wn = wave & 1;
  int lm = lane & 15, kq8 = (lane >> 4) * 8;

  const u8* aPtr = Ab + (size_t)(row0 + (tid >> 1)) * K + ((tid & 1) * 16);
  const u8* bPtr = Bb + (size_t)(col0 + (tid >> 1)) * K + ((tid & 1) * 16);
  u8* ldsAw = &ldsA[wave * 1024];
  u8* ldsBw = &ldsB[wave * 1024];

  float4v acc[4][4] = {};

  for (int k0 = 0; k0 < K; k0 += 32) {
    __syncthreads();
    async16(aPtr + k0, ldsAw);
    async16(bPtr + k0, ldsBw);
    __syncthreads();
    long a8[4], b8[4];
#pragma unroll
    for (int s = 0; s < 4; s++) {
      a8[s] = *(const long*)(&ldsA[(wm * 64 + s * 16 + lm) * 32 + kq8]);
      b8[s] = *(const long*)(&ldsB[(wn * 64 + s * 16 + lm) * 32 + kq8]);
    }
#pragma unroll
    for (int i = 0; i < 4; i++)
#pragma unroll
      for (int j = 0; j < 4; j++)
        acc[i][j] = __builtin_amdgcn_mfma_f32_16x16x32_fp8_fp8(a8[i], b8[j], acc[i][j], 0, 0, 0);
  }

#pragma unroll
  for (int i = 0; i < 4; i++) {
#pragma unroll
    for (int j = 0; j < 4; j++) {
#pragma unroll
      for (int r = 0; r < 4; r++) {
        int grow = row0 + wm * 64 + i * 16 + (lane >> 4) * 4 + r;
        int gcol = col0 + wn * 64 + j * 16 + lm;
        float v = acc[i][j][r] * (1.0f / rs[grow]);
        size_t idx = (size_t)grow * ldc + coloff + gcol;
        if constexpr (MODE == 2) {
          v = v > 0.f ? v : (__expf(v) - 1.f);
          Cout[idx] += v;
        } else {
          atomicAdd(&Cout[idx], 0.25f * v);
        }
      }
    }
  }
}

// ------------------------------------------------- LN layer 0: LN(x) -> elu -> bf16
__global__ __launch_bounds__(256) void ln0_kernel(const float* __restrict__ xin,
                                                  const float* __restrict__ g,
                                                  const float* __restrict__ b,
                                                  u16* __restrict__ h1b) {
  const int C = 2048;
  int n = blockIdx.x, tid = threadIdx.x;
  __shared__ float red[2][4];
  __shared__ float mrs[2];
  float sum = 0.f, sq = 0.f;
  const float* xr = xin + (size_t)n * C;
  for (int c = tid; c < C; c += 256) {
    float x = xr[c];
    sum += x; sq += x * x;
  }
#pragma unroll
  for (int off = 32; off > 0; off >>= 1) { sum += __shfl_down(sum, off); sq += __shfl_down(sq, off); }
  if ((tid & 63) == 0) { red[0][tid >> 6] = sum; red[1][tid >> 6] = sq; }
  __syncthreads();
  if (tid == 0) {
    float s = red[0][0] + red[0][1] + red[0][2] + red[0][3];
    float q = red[1][0] + red[1][1] + red[1][2] + red[1][3];
    float mean = s / C, var = q / C - mean * mean;
    mrs[0] = mean; mrs[1] = rsqrtf(var + 1e-5f);
  }
  __syncthreads();
  float mean = mrs[0], rstd = mrs[1];
  for (int c = tid; c < C; c += 256) {
    float y = (xr[c] - mean) * rstd * g[c] + b[c];
    float z = y > 0.f ? y : (__expf(y) - 1.f);
    h1b[(size_t)n * C + c] = f2bf(z);
  }
}

// ------------------------------------------------- LN layer 1: LN(x) -> out fp32
__global__ __launch_bounds__(256) void ln1_kernel(const float* __restrict__ xin,
                                                  const float* __restrict__ g,
                                                  const float* __restrict__ b,
                                                  float* __restrict__ out) {
  const int C = 768;
  int n = blockIdx.x, tid = threadIdx.x;
  __shared__ float red[2][4];
  __shared__ float mrs[2];
  float sum = 0.f, sq = 0.f;
  const float* xr = xin + (size_t)n * C;
  for (int c = tid; c < C; c += 256) {
    float x = xr[c];
    sum += x; sq += x * x;
  }
#pragma unroll
  for (int off = 32; off > 0; off >>= 1) { sum += __shfl_down(sum, off); sq += __shfl_down(sq, off); }
  if ((tid & 63) == 0) { red[0][tid >> 6] = sum; red[1][tid >> 6] = sq; }
  __syncthreads();
  if (tid == 0) {
    float s = red[0][0] + red[0][1] + red[0][2] + red[0][3];
    float q = red[1][0] + red[1][1] + red[1][2] + red[1][3];
    float mean = s / C, var = q / C - mean * mean;
    mrs[0] = mean; mrs[1] = rsqrtf(var + 1e-5f);
  }
  __syncthreads();
  float mean = mrs[0], rstd = mrs[1];
  for (int c = tid; c < C; c += 256)
    out[(size_t)n * C + c] = (xr[c] - mean) * rstd * g[c] + b[c];
}

// ============================================================================
extern "C" void kernel_launch(void* const* d_in, const int* in_sizes, int n_in,
                              void* d_out, int out_size, void* d_ws, size_t ws_size,
                              hipStream_t stream) {
  (void)in_sizes; (void)n_in; (void)out_size;
  const float* X    = (const float*)d_in[0];
  const int*   adj  = (const int*)d_in[1];
  const float* ew   = (const float*)d_in[2];
  const float* W0   = (const float*)d_in[3];
  const float* a0   = (const float*)d_in[4];
  const float* W1   = (const float*)d_in[5];
  const float* a1   = (const float*)d_in[6];
  const float* rp0w = (const float*)d_in[7];
  const float* rp0b = (const float*)d_in[8];
  const float* rp1w = (const float*)d_in[9];
  const float* rp1b = (const float*)d_in[10];
  const float* ln0g = (const float*)d_in[11];
  const float* ln0b = (const float*)d_in[12];
  const float* ln1g = (const float*)d_in[13];
  const float* ln1b = (const float*)d_in[14];
  float* out = (float*)d_out;
  char* wsb = (char*)d_ws;

  // ---- workspace layout (bytes) ----
  constexpr size_t OFF_XBF   = 0;             // [4096][768]   bf16   6291456
  constexpr size_t OFF_W0T   = 6291456;       // [4][512][768] bf16   3145728
  constexpr size_t OFF_W1T   = 9437184;       // [4][768][2048]bf16  12582912
  constexpr size_t OFF_RP0WT = 22020096;      // [2048][768]   bf16   3145728
  constexpr size_t OFF_RP1WT = 25165824;      // [768][2048]   bf16   3145728
  constexpr size_t OFF_WA0   = 28311552;
  constexpr size_t OFF_WA1   = 28336128;
  constexpr size_t OFF_S0    = 28401664;
  constexpr size_t OFF_S1    = 28532736;
  constexpr size_t OFF_L0    = 28664320;
  constexpr size_t OFF_L1    = 28729856;
  constexpr size_t OFF_H1B   = 28795392;      // [4096][2048] bf16   16777216
  constexpr size_t D         = 45572608;      // dynamic region
  // layer0: WH0T [4][512][4096] fp8 @D (8388608);  RP0 [4096][2048] f32 @D+16777216 (33554432)
  // layer1: WH1T [4][768][4096] fp8 @D (12582912); RP1 [4096][768]  f32 @D+25165824 (12582912)
  constexpr size_t PD        = D + 50331648;  // P region @ 95904256
  constexpr size_t PN        = (size_t)NN * NN;  // 16777216 per head (fp8)

  u16*   XBF   = (u16*)(wsb + OFF_XBF);
  u16*   W0T   = (u16*)(wsb + OFF_W0T);
  u16*   W1T   = (u16*)(wsb + OFF_W1T);
  u16*   RP0WT = (u16*)(wsb + OFF_RP0WT);
  u16*   RP1WT = (u16*)(wsb + OFF_RP1WT);
  float* WA0   = (float*)(wsb + OFF_WA0);
  float* WA1   = (float*)(wsb + OFF_WA1);
  float* S0    = (float*)(wsb + OFF_S0);
  float* S1    = (float*)(wsb + OFF_S1);
  float* L0    = (float*)(wsb + OFF_L0);
  float* L1    = (float*)(wsb + OFF_L1);
  u16*   H1B   = (u16*)(wsb + OFF_H1B);
  u8*    WH0T  = (u8*)(wsb + D);
  float* RP0   = (float*)(wsb + D + 16777216);
  u8*    WH1T  = (u8*)(wsb + D);
  float* RP1   = (float*)(wsb + D + 25165824);
  u8*    P     = (u8*)(wsb + PD);

  // head-group size from available workspace (ws_size constant per session).
  // need(G=4) = 163,013,120 (proven ws >= 230MB in R3, so G=4 expected).
  const int G = (ws_size >= PD + 4 * PN) ? 4 : (ws_size >= PD + 2 * PN) ? 2 : 1;

  // ---- prep ----
  cast_f32_bf16<<<dim3((NN * 768 + 255) / 256), 256, 0, stream>>>(X, XBF, NN * 768);
  transcast_f32<<<dim3(16, 24, 4), 256, 0, stream>>>(W0, W0T, 768, 512);
  transcast_f32<<<dim3(24, 64, 4), 256, 0, stream>>>(W1, W1T, 2048, 768);
  transcast_f32<<<dim3(64, 24, 1), 256, 0, stream>>>(rp0w, RP0WT, 768, 2048);
  transcast_f32<<<dim3(24, 64, 1), 256, 0, stream>>>(rp1w, RP1WT, 2048, 768);

  // ---- layer 0 attention scalars (fp32 exact) ----
  wa_kernel<<<dim3(2 * NHEADS * 768 / 4), 256, 0, stream>>>(W0, a0, WA0, 768, 512);
  s_kernel_f32<<<dim3(2 * NHEADS * NN / 4), 256, 0, stream>>>(X, WA0, S0, 768);

  // ---- layer 0 GEMMs ----
  // Wh0^T[h][o][n] = (X @ W0[h])^T  (fp8 store)
  gemm_bt<4><<<dim3(4, 32, 4), 256, 0, stream>>>(XBF, W0T, WH0T, nullptr,
      768, NN, 0, 0, 0, (size_t)512 * 768, (size_t)512 * NN);
  // RP0 = X @ rp0w + rp0b
  gemm_bt<1><<<dim3(16, 32, 1), 256, 0, stream>>>(XBF, RP0WT, RP0, rp0b,
      768, 2048, 0, 0, 0, 0, 0);
  // per head-group: P' then RP0[:, h*512:(h+1)*512] += elu(P' @ Wh0 / l)
  for (int g = 0; g < NHEADS; g += G) {
    if (G == 4)      pexp_g_kernel<4><<<dim3(NN), 256, 0, stream>>>(adj, ew, S0, P, L0, g);
    else if (G == 2) pexp_g_kernel<2><<<dim3(NN), 256, 0, stream>>>(adj, ew, S0, P, L0, g);
    else             pexp_g_kernel<1><<<dim3(NN), 256, 0, stream>>>(adj, ew, S0, P, L0, g);
    gemm_fp8<2><<<dim3(4, 32, G), 256, 0, stream>>>(P, WH0T + (size_t)g * 512 * NN,
        RP0, L0 + (size_t)g * NN,
        NN, 2048, g * 512, 512, (size_t)NN * NN, (size_t)512 * NN, NN);
  }
  ln0_kernel<<<dim3(NN), 256, 0, stream>>>(RP0, ln0g, ln0b, H1B);

  // ---- layer 1 attention scalars ----
  wa_kernel<<<dim3(2 * NHEADS * 2048 / 4), 256, 0, stream>>>(W1, a1, WA1, 2048, 768);
  s_kernel_bf16<<<dim3(2 * NHEADS * NN / 4), 256, 0, stream>>>(H1B, WA1, S1, 2048);

  // ---- layer 1 GEMMs ----
  // Wh1^T[h][o][n] = (h1 @ W1[h])^T  (fp8 store)
  gemm_bt<4><<<dim3(6, 32, 4), 256, 0, stream>>>(H1B, W1T, WH1T, nullptr,
      2048, NN, 0, 0, 0, (size_t)768 * 2048, (size_t)768 * NN);
  // RP1 = h1 @ rp1w + rp1b
  gemm_bt<1><<<dim3(6, 32, 1), 256, 0, stream>>>(H1B, RP1WT, RP1, rp1b,
      2048, 768, 0, 0, 0, 0, 0);
  // per head-group: P' then RP1 += 0.25 * P' @ Wh1 / l  (atomic across heads)
  for (int g = 0; g < NHEADS; g += G) {
    if (G == 4)      pexp_g_kernel<4><<<dim3(NN), 256, 0, stream>>>(adj, ew, S1, P, L1, g);
    else if (G == 2) pexp_g_kernel<2><<<dim3(NN), 256, 0, stream>>>(adj, ew, S1, P, L1, g);
    else             pexp_g_kernel<1><<<dim3(NN), 256, 0, stream>>>(adj, ew, S1, P, L1, g);
    gemm_fp8<3><<<dim3(6, 32, G), 256, 0, stream>>>(P, WH1T + (size_t)g * 768 * NN,
        RP1, L1 + (size_t)g * NN,
        NN, 768, 0, 0, (size_t)NN * NN, (size_t)768 * NN, NN);
  }
  ln1_kernel<<<dim3(NN), 256, 0, stream>>>(RP1, ln1g, ln1b, out);
}